// Round 5
// baseline (3829.902 us; speedup 1.0000x reference)
//
#include <hip/hip_runtime.h>
#include <hip/hip_fp16.h>
#include <cstdint>
#include <cstddef>

// ---------------------------------------------------------------------------
// CNN (conv1+pool, conv2+pool) -> seq [256][256][32]
// NTM scan: 128 blocks x 1024 threads, 2 batch/block, 1 block/CU.
// Weights fp16 k-pair packed, [pair][c(256)][m(4)] -> cols 4c..4c+3.
//   24 pairs (6 per K-quarter) LDS-resident (96 KB), 136 streamed from L2.
// z-GEMM + head-GEMM via v_dot2_f32_f16. No register weight caching
// (R3/R4 showed the allocator spills it).
// 5 barriers/step: P1 | P2+xt | P3 | P4b+ea | P5'(read+write fused).
// ---------------------------------------------------------------------------

#define MW    20
#define NLOC  128
#define ZC    1024
#define PC    92
#define CLIPV 20.0f

__device__ __forceinline__ float sigmoidf_(float x) { return 1.0f / (1.0f + expf(-x)); }
__device__ __forceinline__ float softplusf_(float x) { return log1pf(expf(x)); }

__device__ __forceinline__ float dot2f(uint32_t w, uint32_t a, float c) {
    asm("v_dot2_f32_f16 %0, %1, %2, %0" : "+v"(c) : "v"(w), "v"(a));
    return c;
}

// K pairs pr = k/2 (K 308 -> 320 pad, 160 pairs):
//   k 0..31 xt, 32..51 reads, 52..307 h, 308..319 zero pad.
__device__ __forceinline__ float wval(const float* wx, const float* wh, int k, int col) {
    if (k < 52)  return wx[k * ZC + col];
    if (k < 308) return wh[(k - 52) * ZC + col];
    return 0.0f;
}
__device__ __forceinline__ uint32_t packpr(const float* wx, const float* wh, int pr, int col) {
    __half2 h = __floats2half2_rn(wval(wx, wh, 2 * pr, col), wval(wx, wh, 2 * pr + 1, col));
    return *reinterpret_cast<uint32_t*>(&h);
}

// WG layout: u32 idx = (pair*256 + c)*4 + m  -> col = 4c + m.
__global__ __launch_bounds__(256) void prep_pack(const float* __restrict__ wx,
                                                 const float* __restrict__ wh,
                                                 const float* __restrict__ hw,
                                                 uint32_t* __restrict__ WG,     // [160][256][4]
                                                 uint32_t* __restrict__ hw2G) { // [128][92]
    int idx = blockIdx.x * 256 + threadIdx.x;
    if (idx < 163840) {
        int m = idx & 3, cc = (idx >> 2) & 255, pair = idx >> 10;
        WG[idx] = packpr(wx, wh, pair, cc * 4 + m);
    } else if (idx < 163840 + 11776) {
        int q = idx - 163840;
        int up = q / 92, col = q - up * 92;
        __half2 h = __floats2half2_rn(hw[(2 * up) * PC + col], hw[(2 * up + 1) * PC + col]);
        hw2G[q] = *reinterpret_cast<uint32_t*>(&h);
    }
}

// conv1 3x3 (1->16) SAME + relu + maxpool2
__global__ __launch_bounds__(256) void conv1_pool(const float* __restrict__ in,
                                                  const float* __restrict__ w,
                                                  const float* __restrict__ bias,
                                                  float* __restrict__ out) {
    int idx = blockIdx.x * 256 + threadIdx.x;
    if (idx >= 256 * 32 * 32 * 16) return;
    int c = idx & 15, x = (idx >> 4) & 31, y = (idx >> 9) & 31, b = idx >> 14;
    const float* inb = in + (size_t)b * 4096;
    float bv = bias[c];
    float mx = 0.0f;
    #pragma unroll
    for (int dy = 0; dy < 2; ++dy)
    #pragma unroll
    for (int dx = 0; dx < 2; ++dx) {
        int oy = 2 * y + dy, ox = 2 * x + dx;
        float s = bv;
        #pragma unroll
        for (int ky = 0; ky < 3; ++ky) {
            int iy = oy + ky - 1;
            if (iy < 0 || iy > 63) continue;
            #pragma unroll
            for (int kx = 0; kx < 3; ++kx) {
                int ix = ox + kx - 1;
                if (ix < 0 || ix > 63) continue;
                s = fmaf(inb[iy * 64 + ix], w[(ky * 3 + kx) * 16 + c], s);
            }
        }
        mx = fmaxf(mx, fmaxf(s, 0.0f));
    }
    out[idx] = mx;
}

// conv2 3x3 (16->32) SAME + relu + maxpool2
__global__ __launch_bounds__(256) void conv2_pool(const float* __restrict__ p1,
                                                  const float* __restrict__ w,
                                                  const float* __restrict__ bias,
                                                  float* __restrict__ seq) {
    int idx = blockIdx.x * 256 + threadIdx.x;
    if (idx >= 256 * 16 * 16 * 32) return;
    int c = idx & 31, x = (idx >> 5) & 15, y = (idx >> 9) & 15, b = idx >> 13;
    const float* pb = p1 + (size_t)b * (32 * 32 * 16);
    float bv = bias[c];
    float mx = 0.0f;
    #pragma unroll
    for (int dy = 0; dy < 2; ++dy)
    #pragma unroll
    for (int dx = 0; dx < 2; ++dx) {
        int oy = 2 * y + dy, ox = 2 * x + dx;
        float s = bv;
        for (int ky = 0; ky < 3; ++ky) {
            int iy = oy + ky - 1;
            if (iy < 0 || iy > 31) continue;
            for (int kx = 0; kx < 3; ++kx) {
                int ix = ox + kx - 1;
                if (ix < 0 || ix > 31) continue;
                const float* pin = pb + (iy * 32 + ix) * 16;
                const float* pw  = w + (ky * 3 + kx) * 16 * 32 + c;
                #pragma unroll
                for (int ci2 = 0; ci2 < 16; ++ci2)
                    s = fmaf(pin[ci2], pw[ci2 * 32], s);
            }
        }
        mx = fmaxf(mx, fmaxf(s, 0.0f));
    }
    seq[idx] = mx;
}

// ---------------------------------------------------------------------------
// Persistent NTM scan: 2 batch/block, 1024 threads.
// ---------------------------------------------------------------------------
#define PSCLIP(b_, col_) fminf(fmaxf(pp[0][b_][col_] + pp[1][b_][col_] + pp[2][b_][col_] + pp[3][b_][col_] + hb[col_], -CLIPV), CLIPV)

__global__ __launch_bounds__(1024, 4) void ntm_scan5(
    const float* __restrict__ seq,
    const uint32_t* __restrict__ WG,
    const uint32_t* __restrict__ hw2G,
    const float* __restrict__ lb,
    const float* __restrict__ hb,
    const float* __restrict__ ow,
    const float* __restrict__ ob,
    const float* __restrict__ dw,
    const float* __restrict__ db,
    float* __restrict__ out)          // [256][2]
{
    __shared__ uint4 Wl4[24 * 256];                   // 98304 B (pairs p<6 per kq)
    __shared__ float zpart[4][2][ZC];                 // 32768 B
    __shared__ __align__(16) _Float16 ci2h[2][320];   // 1280 B
    __shared__ float Msh[2][MW][132];                 // 21120 B
    __shared__ float wprev[2][2][NLOC];               // 2048 B
    __shared__ float pp[4][2][PC];                    // 2944 B
    __shared__ float evs[2][MW], avs[2][MW];          // 320 B
    __shared__ float rds[2][MW];                      // 160 B
    __shared__ float o8[2][8];                        // 64 B
    // total ~159 KB

    const int t = threadIdx.x;
    const int bs0 = blockIdx.x * 2;
    const int kq = t >> 8, c = t & 255;
    const uint4* WG4 = (const uint4*)WG;

    // ---- stage LDS weights: for each kq, pairs p 0..5 ----
    for (int i = t; i < 6144; i += 1024) {
        int lkq = i / 1536, rem = i - lkq * 1536;
        int p = rem >> 8, cc = rem & 255;
        Wl4[i] = WG4[(lkq * 40 + p) * 256 + cc];
    }

    // ---- init state ----
    for (int i = t; i < 2 * 320; i += 1024) {
        int b = i / 320, k = i - b * 320;
        _Float16 v;
        if (k < 32)      v = (_Float16)seq[(size_t)(bs0 + b) * 8192 + k];
        else if (k < 52) v = (_Float16)1e-6f;
        else             v = (_Float16)0.0f;
        ci2h[b][k] = v;
    }
    for (int i = t; i < 2 * MW * 132; i += 1024) {
        int b = i / (MW * 132), r = i - b * (MW * 132);
        Msh[b][r / 132][r - (r / 132) * 132] = 1e-6f;
    }
    if (t < 512) {
        int b = t >> 8, r = t & 255;
        wprev[b][r >> 7][r & 127] = 1.0f / 128.0f;
    }
    float c_reg = 0.0f;   // cell state: thread t<512 owns (b=t>>8, u=t&255)
    __syncthreads();

    const uint32_t* ci2u0 = (const uint32_t*)&ci2h[0][0];
    const uint32_t* ci2u1 = (const uint32_t*)&ci2h[1][0];

    for (int step = 0; step < 256; ++step) {
        // ---- P1: z = ci @ [Wx;Wh] via dot2; kq K-quarter, cols 4c..4c+3 ----
        {
            float acc0[4] = {0.f, 0.f, 0.f, 0.f};
            float acc1[4] = {0.f, 0.f, 0.f, 0.f};
            const uint4* cA = (const uint4*)(ci2u0 + 40 * kq);
            const uint4* cB = (const uint4*)(ci2u1 + 40 * kq);
            #pragma unroll
            for (int cc = 0; cc < 10; ++cc) {
                uint4 a4 = cA[cc];
                uint4 b4 = cB[cc];
                uint32_t aa[4] = {a4.x, a4.y, a4.z, a4.w};
                uint32_t bb[4] = {b4.x, b4.y, b4.z, b4.w};
                #pragma unroll
                for (int q = 0; q < 4; ++q) {
                    const int p = cc * 4 + q;
                    uint4 w = (p < 6) ? Wl4[(kq * 6 + p) * 256 + c]
                                      : WG4[(kq * 40 + p) * 256 + c];
                    acc0[0] = dot2f(w.x, aa[q], acc0[0]);
                    acc0[1] = dot2f(w.y, aa[q], acc0[1]);
                    acc0[2] = dot2f(w.z, aa[q], acc0[2]);
                    acc0[3] = dot2f(w.w, aa[q], acc0[3]);
                    acc1[0] = dot2f(w.x, bb[q], acc1[0]);
                    acc1[1] = dot2f(w.y, bb[q], acc1[1]);
                    acc1[2] = dot2f(w.z, bb[q], acc1[2]);
                    acc1[3] = dot2f(w.w, bb[q], acc1[3]);
                }
            }
            *reinterpret_cast<float4*>(&zpart[kq][0][4 * c]) =
                make_float4(acc0[0], acc0[1], acc0[2], acc0[3]);
            *reinterpret_cast<float4*>(&zpart[kq][1][4 * c]) =
                make_float4(acc1[0], acc1[1], acc1[2], acc1[3]);
        }
        __syncthreads();   // B1

        // ---- P2: LSTM update (+ next-xt prefetch on spare threads) ----
        if (t < 512) {
            int b = t >> 8, u = t & 255;
            float zi = lb[u], zf = lb[256 + u], zg = lb[512 + u], zo = lb[768 + u];
            #pragma unroll
            for (int q = 0; q < 4; ++q) {
                zi += zpart[q][b][u];       zf += zpart[q][b][256 + u];
                zg += zpart[q][b][512 + u]; zo += zpart[q][b][768 + u];
            }
            float cg = sigmoidf_(zf) * c_reg + sigmoidf_(zi) * tanhf(zg);
            c_reg = cg;
            ci2h[b][52 + u] = (_Float16)(sigmoidf_(zo) * tanhf(cg));
        } else if (t < 576 && step < 255) {
            int q = t - 512, b = q >> 5, cc = q & 31;
            ci2h[b][cc] = (_Float16)seq[(size_t)(bs0 + b) * 8192 + (size_t)(step + 1) * 32 + cc];
        }
        __syncthreads();   // B2

        // ---- P3: head-param GEMM partials via dot2 (4-way u split) ----
        if (t < 736) {
            int kq2 = t / 184, r = t - kq2 * 184, b = r / 92, col = r - b * 92;
            const uint32_t* hwp = hw2G + kq2 * 32 * 92 + col;
            const uint32_t* hbp = (b ? ci2u1 : ci2u0) + 26 + kq2 * 32;
            float s = 0.0f;
            #pragma unroll 8
            for (int uu = 0; uu < 32; ++uu)
                s = dot2f(hwp[uu * 92], hbp[uu], s);
            pp[kq2][b][col] = s;
        }
        __syncthreads();   // B3

        // ---- P4b: addressing (t<256, one wave per (b,hh)); evs/avs on 256..335 ----
        if (t < 256) {
            const int l = t & 63;
            const int b = t >> 7, hh = (t >> 6) & 1;
            const int hc = hh * 26;
            float beta  = softplusf_(PSCLIP(b, hc + 20));
            float g     = sigmoidf_(PSCLIP(b, hc + 21));
            float s0r = PSCLIP(b, hc + 22), s1r = PSCLIP(b, hc + 23), s2r = PSCLIP(b, hc + 24);
            float mS = fmaxf(s0r, fmaxf(s1r, s2r));
            float q0 = expf(s0r - mS), q1 = expf(s1r - mS), q2 = expf(s2r - mS);
            float qin = 1.0f / (q0 + q1 + q2);
            float sh0 = q0 * qin, sh1 = q1 * qin, sh2 = q2 * qin;
            float gamma = softplusf_(PSCLIP(b, hc + 25)) + 1.0f;

            float kvv = (l < 20) ? tanhf(PSCLIP(b, hc + l)) : 0.0f;
            float kn2 = kvv * kvv;
            #pragma unroll
            for (int o = 1; o < 64; o <<= 1) kn2 += __shfl_xor(kn2, o, 64);
            float kden = sqrtf(kn2) + 1e-8f;

            float d0 = 0, d1 = 0, m20 = 0, m21 = 0;
            #pragma unroll
            for (int wi = 0; wi < 20; ++wi) {
                float kk = __shfl(kvv, wi, 64);
                float2 mv = *reinterpret_cast<const float2*>(&Msh[b][wi][2 * l]);
                d0  = fmaf(kk, mv.x, d0);      d1  = fmaf(kk, mv.y, d1);
                m20 = fmaf(mv.x, mv.x, m20);   m21 = fmaf(mv.y, mv.y, m21);
            }
            float x0 = beta * (d0 / ((sqrtf(m20) + 1e-8f) * kden));
            float x1 = beta * (d1 / ((sqrtf(m21) + 1e-8f) * kden));
            float mx = fmaxf(x0, x1);
            #pragma unroll
            for (int o = 1; o < 64; o <<= 1) mx = fmaxf(mx, __shfl_xor(mx, o, 64));
            float e0 = expf(x0 - mx), e1 = expf(x1 - mx);
            float se = e0 + e1;
            #pragma unroll
            for (int o = 1; o < 64; o <<= 1) se += __shfl_xor(se, o, 64);
            float inv = 1.0f / se;
            float2 wpv = *reinterpret_cast<const float2*>(&wprev[b][hh][2 * l]);
            float wg0 = g * (e0 * inv) + (1.0f - g) * wpv.x;
            float wg1 = g * (e1 * inv) + (1.0f - g) * wpv.y;
            float wgm = __shfl(wg1, (l + 63) & 63, 64);
            float wgp = __shfl(wg0, (l + 1) & 63, 64);
            float wt0 = sh0 * wg1 + sh1 * wg0 + sh2 * wgm;
            float wt1 = sh0 * wgp + sh1 * wg1 + sh2 * wg0;
            float wpw0 = expf(gamma * logf(wt0 + 1e-8f));
            float wpw1 = expf(gamma * logf(wt1 + 1e-8f));
            float ssum = wpw0 + wpw1;
            #pragma unroll
            for (int o = 1; o < 64; o <<= 1) ssum += __shfl_xor(ssum, o, 64);
            float rin = 1.0f / ssum;
            *reinterpret_cast<float2*>(&wprev[b][hh][2 * l]) = make_float2(wpw0 * rin, wpw1 * rin);
        } else if (t < 336) {
            int q = t - 256, b = q / 40, r2 = q - b * 40;
            if (r2 < 20) evs[b][r2]      = sigmoidf_(PSCLIP(b, 52 + r2));
            else         avs[b][r2 - 20] = tanhf(PSCLIP(b, 72 + (r2 - 20)));
        }
        __syncthreads();   // B4

        // ---- P5': fused read-dot + erase/add (each M element touched once) ----
        if (t < 640) {
            int g16 = t >> 4, l16 = t & 15;
            int b = g16 / 20, wi = g16 - b * 20;
            int n0 = l16 * 8;
            float ev = evs[b][wi], av = avs[b][wi];
            float s = 0.0f;
            #pragma unroll
            for (int n = n0; n < n0 + 8; ++n) {
                float mv = Msh[b][wi][n];
                s = fmaf(wprev[b][0][n], mv, s);
                float wwn = wprev[b][1][n];
                Msh[b][wi][n] = mv * (1.0f - wwn * ev) + wwn * av;
            }
            #pragma unroll
            for (int o = 1; o < 16; o <<= 1) s += __shfl_xor(s, o, 64);
            if (l16 == 0) { rds[b][wi] = s; ci2h[b][32 + wi] = (_Float16)s; }
        }
        __syncthreads();   // B5
    }

    // ---- final NTM output head + dense + softmax ----
    if (t < 16) {
        int b = t >> 3, o = t & 7;
        float s = ob[o];
        for (int u = 0; u < 256; ++u) s = fmaf((float)ci2h[b][52 + u], ow[u * 8 + o], s);
        #pragma unroll
        for (int wi = 0; wi < 20; ++wi) s = fmaf(rds[b][wi], ow[(256 + wi) * 8 + o], s);
        o8[b][o] = fminf(fmaxf(s, -CLIPV), CLIPV);
    }
    __syncthreads();
    if (t < 2) {
        float l0 = db[0], l1 = db[1];
        #pragma unroll
        for (int k = 0; k < 8; ++k) {
            float v = o8[t][k];
            l0 = fmaf(v, dw[k * 2 + 0], l0);
            l1 = fmaf(v, dw[k * 2 + 1], l1);
        }
        float m = fmaxf(l0, l1);
        float q0 = expf(l0 - m), q1 = expf(l1 - m);
        float inv = 1.0f / (q0 + q1);
        out[(bs0 + t) * 2 + 0] = q0 * inv;
        out[(bs0 + t) * 2 + 1] = q1 * inv;
    }
}

extern "C" void kernel_launch(void* const* d_in, const int* in_sizes, int n_in,
                              void* d_out, int out_size, void* d_ws, size_t ws_size,
                              hipStream_t stream) {
    const float* inputs = (const float*)d_in[0];
    const float* c1w = (const float*)d_in[1];
    const float* c1b = (const float*)d_in[2];
    const float* c2w = (const float*)d_in[3];
    const float* c2b = (const float*)d_in[4];
    const float* lwx = (const float*)d_in[5];
    const float* lwh = (const float*)d_in[6];
    const float* lb  = (const float*)d_in[7];
    const float* hw  = (const float*)d_in[8];
    const float* hb  = (const float*)d_in[9];
    const float* ow  = (const float*)d_in[10];
    const float* ob  = (const float*)d_in[11];
    const float* dw  = (const float*)d_in[12];
    const float* db  = (const float*)d_in[13];
    float* out = (float*)d_out;

    float* ws    = (float*)d_ws;
    float* p1    = ws;                             // 4,194,304 f
    float* seq   = ws + 4194304;                   // 2,097,152 f
    uint32_t* WG    = (uint32_t*)(ws + 6291456);   // 163,840 u32
    uint32_t* hw2G  = WG + 163840;                 //  11,776 u32

    hipLaunchKernelGGL(prep_pack,  dim3(686),   dim3(256),  0, stream, lwx, lwh, hw, WG, hw2G);
    hipLaunchKernelGGL(conv1_pool, dim3(16384), dim3(256),  0, stream, inputs, c1w, c1b, p1);
    hipLaunchKernelGGL(conv2_pool, dim3(8192),  dim3(256),  0, stream, p1, c2w, c2b, seq);
    hipLaunchKernelGGL(ntm_scan5,  dim3(128),   dim3(1024), 0, stream,
                       seq, WG, hw2G, lb, hb, ow, ob, dw, db, out);
}